// Round 1
// baseline (271.822 us; speedup 1.0000x reference)
//
#include <hip/hip_runtime.h>

// LaplacianRegularizer3D via expanded-square identity:
//   loss = 2*[ sum_p nk*ni*nj*x^2  -  sum_p x^2  -  2*sum_{s in 13 fwd shifts} sum_p x[p]*x[p+s] ]
// nk,ni,nj in {2,3} = #in-bounds offsets per axis. Cross terms cost 1 fma each
// (vs sub+fma in the difference form) -> ~1.7x fewer VALU ops, same memory.
// One wave == one full row (64 lanes x float4 = 256 elems); all 8 k-planes in
// registers; j-edges via shuffle. Two-stage reduction: block partials -> d_ws,
// then a 1-block kernel sums 6144 partials (no same-address atomics).

constexpr int WIDTH  = 256;
constexpr int HWs    = 256 * 256;
constexpr int NBLOCK = 8 * 12 * 256 / 4;   // 6144

__global__ __launch_bounds__(256, 2) void lap3d(const float* __restrict__ f,
                                                float* __restrict__ partial) {
    const int tid  = threadIdx.x;
    const int lane = tid & 63;
    const int wid  = tid >> 6;
    const int row  = blockIdx.x * 4 + wid;   // (b*12+c)*256 + i
    const int i    = row & 255;
    const int bc   = row >> 8;               // 0..95
    const float* base = f + (size_t)bc * 8 * HWs + (size_t)i * WIDTH + (size_t)lane * 4;

    const bool has_down  = (i < 255);
    const bool has_right = (lane < 63);
    const bool has_left  = (lane > 0);

    float o[8][4], nx[8][4];
#pragma unroll
    for (int k = 0; k < 8; ++k) {
        float4 v = *reinterpret_cast<const float4*>(base + k * HWs);
        o[k][0] = v.x; o[k][1] = v.y; o[k][2] = v.z; o[k][3] = v.w;
    }
    if (has_down) {
#pragma unroll
        for (int k = 0; k < 8; ++k) {
            float4 v = *reinterpret_cast<const float4*>(base + k * HWs + WIDTH);
            nx[k][0] = v.x; nx[k][1] = v.y; nx[k][2] = v.z; nx[k][3] = v.w;
        }
    } else {
#pragma unroll
        for (int k = 0; k < 8; ++k) { nx[k][0] = nx[k][1] = nx[k][2] = nx[k][3] = 0.f; }
    }

    // j-edge values from neighboring lanes (wave spans the whole row)
    float eo[8], nl[8], nr[8];
#pragma unroll
    for (int k = 0; k < 8; ++k) {
        eo[k] = __shfl_down(o[k][0], 1);   // own row, j0+4
        nr[k] = __shfl_down(nx[k][0], 1);  // row i+1, j0+4
        nl[k] = __shfl_up(nx[k][3], 1);    // row i+1, j0-1
    }

    // ---- cross-correlation terms: sum over 13 forward shifts of x[p]*x[p+s] ----
    float cross = 0.f;

    // s = (1,0,0)
#pragma unroll
    for (int k = 0; k < 7; ++k)
#pragma unroll
        for (int m = 0; m < 4; ++m) cross = fmaf(o[k][m], o[k + 1][m], cross);

    // s = (dk,0,1)
#pragma unroll
    for (int k = 0; k < 8; ++k)
#pragma unroll
        for (int dk = -1; dk <= 1; ++dk) {
            const int kk = k + dk;
            if (kk < 0 || kk > 7) continue;
#pragma unroll
            for (int m = 0; m < 3; ++m) cross = fmaf(o[k][m], o[kk][m + 1], cross);
            if (has_right) cross = fmaf(o[k][3], eo[kk], cross);
        }

    // s = (dk,1,dj)
    if (has_down) {
#pragma unroll
        for (int k = 0; k < 8; ++k)
#pragma unroll
            for (int dk = -1; dk <= 1; ++dk) {
                const int kk = k + dk;
                if (kk < 0 || kk > 7) continue;
#pragma unroll
                for (int m = 0; m < 4; ++m) cross = fmaf(o[k][m], nx[kk][m], cross);     // dj=0
#pragma unroll
                for (int m = 0; m < 3; ++m) cross = fmaf(o[k][m], nx[kk][m + 1], cross); // dj=+1
                if (has_right) cross = fmaf(o[k][3], nr[kk], cross);
#pragma unroll
                for (int m = 1; m < 4; ++m) cross = fmaf(o[k][m], nx[kk][m - 1], cross); // dj=-1
                if (has_left) cross = fmaf(o[k][0], nl[kk], cross);
            }
    }

    // ---- weighted squares: ni * sum_m nj[m] * (3*sum_k x^2 - (x[0]^2+x[7]^2)),
    //      and C0 = sum x^2 ----
    const float ni = (i == 0 || i == 255) ? 2.f : 3.f;
    float sqw = 0.f, c0 = 0.f;
#pragma unroll
    for (int m = 0; m < 4; ++m) {
        float sa = 0.f;
#pragma unroll
        for (int k = 0; k < 8; ++k) sa = fmaf(o[k][m], o[k][m], sa);
        const float se = fmaf(o[0][m], o[0][m], o[7][m] * o[7][m]);
        const int   j  = lane * 4 + m;
        const float nj = (j == 0 || j == 255) ? 2.f : 3.f;
        sqw = fmaf(nj, fmaf(3.f, sa, -se), sqw);
        c0 += sa;
    }

    // per-thread partial; final kernel multiplies by 2
    float acc = fmaf(ni, sqw, -fmaf(2.f, cross, c0));

    // Wave reduce, cross-wave via LDS, one partial per block (no atomics).
#pragma unroll
    for (int off = 32; off > 0; off >>= 1) acc += __shfl_down(acc, off);

    __shared__ float wsum[4];
    if (lane == 0) wsum[wid] = acc;
    __syncthreads();
    if (tid == 0) partial[blockIdx.x] = wsum[0] + wsum[1] + wsum[2] + wsum[3];
}

__global__ __launch_bounds__(256) void lap3d_reduce(const float* __restrict__ partial,
                                                    float* __restrict__ out) {
    float s = 0.f;
    for (int i = threadIdx.x; i < NBLOCK; i += 256) s += partial[i];
#pragma unroll
    for (int off = 32; off > 0; off >>= 1) s += __shfl_down(s, off);
    __shared__ float w[4];
    if ((threadIdx.x & 63) == 0) w[threadIdx.x >> 6] = s;
    __syncthreads();
    if (threadIdx.x == 0) out[0] = 2.0f * (w[0] + w[1] + w[2] + w[3]);
}

extern "C" void kernel_launch(void* const* d_in, const int* in_sizes, int n_in,
                              void* d_out, int out_size, void* d_ws, size_t ws_size,
                              hipStream_t stream) {
    const float* f = (const float*)d_in[0];
    float* partial = (float*)d_ws;            // 6144 floats, well under ws_size
    float* out = (float*)d_out;
    lap3d<<<dim3(NBLOCK), dim3(256), 0, stream>>>(f, partial);
    lap3d_reduce<<<dim3(1), dim3(256), 0, stream>>>(partial, out);
}